// Round 6
// baseline (1398.964 us; speedup 1.0000x reference)
//
#include <hip/hip_runtime.h>
#include <cmath>

#define NE   16
#define DIN  256
#define DHID 512
#define NROW 524288
#define ROWS 64
#define TAU  4e-4f

typedef __bf16 bf16;
typedef bf16  bf16x8 __attribute__((ext_vector_type(8)));
typedef float f32x4  __attribute__((ext_vector_type(4)));

template<int CTRL>
__device__ __forceinline__ float dpp_xor_add(float v) {
    int s = __builtin_amdgcn_update_dpp(0, __float_as_int(v), CTRL, 0xF, 0xF, true);
    return v + __int_as_float(s);
}
template<int OFF>
__device__ __forceinline__ float swz_xor_add(float v) {
    int s = __builtin_amdgcn_ds_swizzle(__float_as_int(v), OFF);
    return v + __int_as_float(s);
}
__device__ __forceinline__ void load_lds16(const void* g, void* l) {
    __builtin_amdgcn_global_load_lds(
        (const __attribute__((address_space(1))) void*)g,
        (__attribute__((address_space(3))) void*)l,
        16, 0, 0);
}

// ---- K0: split w1 -> bf16 hi/lo in per-(ch,ksk) LDS-image layout ----
// slice (ch,ksk): 8192 bf16 = [pl 2][g 4][col 128][j 8], slices consecutive.
__global__ __launch_bounds__(256)
void split_w1_k(const float* __restrict__ w1, bf16* __restrict__ w1t) {
    int i = blockIdx.x * 256 + threadIdx.x;   // 131072 elements
    int col = i & 511, k = i >> 9;
    float v = w1[k * DHID + col];
    bf16 h = (bf16)v;
    bf16 l = (bf16)(v - (float)h);
    int ch = col >> 7, cl = col & 127, ksk = k >> 5, g = (k >> 3) & 3, j = k & 7;
    size_t base = (size_t)(ch * 8 + ksk) * 8192;
    w1t[base +        g * 1024 + cl * 8 + j] = h;
    w1t[base + 4096 + g * 1024 + cl * 8 + j] = l;
}

// ---- Pass A: x-resident-LDS MFMA router + gap flagging ----
__global__ __launch_bounds__(256, 2)
void router_mfma_k(const float* __restrict__ x,
                   const float* __restrict__ b1,
                   const float* __restrict__ w2,
                   const float* __restrict__ b2,
                   float* __restrict__ out,
                   const bf16* __restrict__ w1t,
                   unsigned* __restrict__ cnt,
                   unsigned* __restrict__ ids,
                   unsigned cap)
{
    __shared__ __align__(16) bf16 xh_s[8][4][ROWS][8];   // 32 KB  [ksk][g][row][j]
    __shared__ __align__(16) bf16 xl_s[8][4][ROWS][8];   // 32 KB
    __shared__ __align__(16) bf16 w_s[2][4][128][8];     // 16 KB  [pl][g][col][j]
    float* l_lds = (float*)&w_s[0][0][0][0];             // overlay after main loop

    const int t    = threadIdx.x;
    const int lane = t & 63;
    const int wv   = t >> 6;
    const int wr   = wv >> 1;          // row-half 0..1 (rows 32wr..+32)
    const int wc   = wv & 1;           // col-half 0..1 (cols 64wc..+64)
    const int c    = lane & 15;        // frag lane coord / owned expert
    const int g    = lane >> 4;        // k sub-block / C row sub-group
    const long long row0 = (long long)blockIdx.x * ROWS;

    // ---- stage x (full K) split hi/lo, ONCE ----
    {
        const int r = t & 63;
        const float* xg = x + (row0 + r) * DIN + wv * 64;
#pragma unroll
        for (int m = 0; m < 8; ++m) {
            float4 v0 = ((const float4*)xg)[2 * m];
            float4 v1 = ((const float4*)xg)[2 * m + 1];
            int k   = wv * 64 + m * 8;
            int ksk = k >> 5, gg = (k >> 3) & 3;
            float vv[8] = {v0.x, v0.y, v0.z, v0.w, v1.x, v1.y, v1.z, v1.w};
            bf16 hb[8], lb[8];
#pragma unroll
            for (int q = 0; q < 8; ++q) {
                hb[q] = (bf16)vv[q];
                lb[q] = (bf16)(vv[q] - (float)hb[q]);
            }
            *(bf16x8*)&xh_s[ksk][gg][r][0] = *(const bf16x8*)hb;
            *(bf16x8*)&xl_s[ksk][gg][r][0] = *(const bf16x8*)lb;
        }
    }

    float lg[8];
#pragma unroll
    for (int i = 0; i < 8; ++i) lg[i] = 0.f;

    for (int ch = 0; ch < 4; ++ch) {
        f32x4 acc[2][4];
#pragma unroll
        for (int ti = 0; ti < 2; ++ti)
#pragma unroll
            for (int tj = 0; tj < 4; ++tj)
#pragma unroll
                for (int r = 0; r < 4; ++r) acc[ti][tj][r] = 0.f;

        for (int ksk = 0; ksk < 8; ++ksk) {
            __syncthreads();   // prev-iter w reads done (iter 0: x-stage visible)
            // ---- stage w slice (16 KB, contiguous, L2-hot) ----
            {
                const bf16* src = w1t + (size_t)(ch * 8 + ksk) * 8192
                                      + wv * 2048 + lane * 8;
                bf16* dst = ((bf16*)w_s) + wv * 2048;   // wave-uniform base
#pragma unroll
                for (int p = 0; p < 4; ++p)
                    load_lds16(src + p * 512, dst + p * 512);
            }
            __syncthreads();   // barrier drains vmcnt: w_s ready

            // ---- MFMA: 32 rows x 64 cols x 32 k, bf16x3 ----
            bf16x8 ah[2], al[2];
#pragma unroll
            for (int ti = 0; ti < 2; ++ti) {
                ah[ti] = *(const bf16x8*)&xh_s[ksk][g][32 * wr + 16 * ti + c][0];
                al[ti] = *(const bf16x8*)&xl_s[ksk][g][32 * wr + 16 * ti + c][0];
            }
#pragma unroll
            for (int tj = 0; tj < 4; ++tj) {
                bf16x8 bh = *(const bf16x8*)&w_s[0][g][64 * wc + 16 * tj + c][0];
                bf16x8 bl = *(const bf16x8*)&w_s[1][g][64 * wc + 16 * tj + c][0];
#pragma unroll
                for (int ti = 0; ti < 2; ++ti) {
                    acc[ti][tj] = __builtin_amdgcn_mfma_f32_16x16x32_bf16(ah[ti], bh, acc[ti][tj], 0, 0, 0);
                    acc[ti][tj] = __builtin_amdgcn_mfma_f32_16x16x32_bf16(ah[ti], bl, acc[ti][tj], 0, 0, 0);
                    acc[ti][tj] = __builtin_amdgcn_mfma_f32_16x16x32_bf16(al[ti], bh, acc[ti][tj], 0, 0, 0);
                }
            }
        }

        // ---- bias + relu (C row = 32wr+16ti+4g+r, col = 128ch+64wc+16tj+c) ----
#pragma unroll
        for (int tj = 0; tj < 4; ++tj) {
            float bj = b1[128 * ch + 64 * wc + 16 * tj + c];
#pragma unroll
            for (int ti = 0; ti < 2; ++ti)
#pragma unroll
                for (int r = 0; r < 4; ++r)
                    acc[ti][tj][r] = fmaxf(acc[ti][tj][r] + bj, 0.f);
        }

        // ---- fused layer 2 partials (this wave's col-half) ----
#pragma unroll 1
        for (int e = 0; e < NE; ++e) {
            float p[8];
#pragma unroll
            for (int i = 0; i < 8; ++i) p[i] = 0.f;
#pragma unroll
            for (int tj = 0; tj < 4; ++tj) {
                float wvv = w2[(128 * ch + 64 * wc + 16 * tj + c) * NE + e];
#pragma unroll
                for (int ti = 0; ti < 2; ++ti)
#pragma unroll
                    for (int r = 0; r < 4; ++r)
                        p[ti * 4 + r] = fmaf(acc[ti][tj][r], wvv, p[ti * 4 + r]);
            }
#pragma unroll
            for (int i = 0; i < 8; ++i) p[i] = dpp_xor_add<0xB1>(p[i]);
#pragma unroll
            for (int i = 0; i < 8; ++i) p[i] = dpp_xor_add<0x4E>(p[i]);
#pragma unroll
            for (int i = 0; i < 8; ++i) p[i] = swz_xor_add<0x101F>(p[i]);
#pragma unroll
            for (int i = 0; i < 8; ++i) p[i] = swz_xor_add<0x201F>(p[i]);
            if (c == e) {
#pragma unroll
                for (int i = 0; i < 8; ++i) lg[i] += p[i];
            }
        }
    }

    // ---- combine col-halves (fixed order: wc0 writes, wc1 adds) ----
    __syncthreads();                 // all w_s reads done -> safe to overlay
    if (wc == 0) {
        float b2c = b2[c];
#pragma unroll
        for (int ti = 0; ti < 2; ++ti)
#pragma unroll
            for (int r = 0; r < 4; ++r)
                l_lds[(32 * wr + 16 * ti + 4 * g + r) * (NE + 1) + c] = lg[ti * 4 + r] + b2c;
    }
    __syncthreads();
    if (wc == 1) {
#pragma unroll
        for (int ti = 0; ti < 2; ++ti)
#pragma unroll
            for (int r = 0; r < 4; ++r)
                l_lds[(32 * wr + 16 * ti + 4 * g + r) * (NE + 1) + c] += lg[ti * 4 + r];
    }
    __syncthreads();

    // ---- per-row top-2 + TAU flag + masked softmax ----
    if (t < ROWS) {
        float l[NE];
#pragma unroll
        for (int e = 0; e < NE; ++e) l[e] = l_lds[t * (NE + 1) + e];

        float m1 = -INFINITY; int i1 = 0;
#pragma unroll
        for (int e = 0; e < NE; ++e)
            if (l[e] > m1) { m1 = l[e]; i1 = e; }
        float m2 = -INFINITY; int i2 = -1;
#pragma unroll
        for (int e = 0; e < NE; ++e)
            if (e != i1 && l[e] > m2) { m2 = l[e]; i2 = e; }
        float m3 = -INFINITY;
#pragma unroll
        for (int e = 0; e < NE; ++e)
            if (e != i1 && e != i2 && l[e] > m3) m3 = l[e];

        if (m2 - m3 < TAU) {
            unsigned idx = atomicAdd(cnt, 1u);
            if (idx < cap) ids[idx] = (unsigned)(row0 + t);
        }

        float s[NE];
#pragma unroll
        for (int e = 0; e < NE; ++e)
            s[e] = (e == i1 || e == i2) ? l[e] : 0.f;
        float mx = s[0];
#pragma unroll
        for (int e = 1; e < NE; ++e) mx = fmaxf(mx, s[e]);
        float ex[NE];
        float sum = 0.f;
#pragma unroll
        for (int e = 0; e < NE; ++e) { ex[e] = expf(s[e] - mx); sum += ex[e]; }
        float r = 1.f / sum;
        float4 o0 = {ex[0] * r, ex[1] * r, ex[2] * r, ex[3] * r};
        float4 o1 = {ex[4] * r, ex[5] * r, ex[6] * r, ex[7] * r};
        float4 o2 = {ex[8] * r, ex[9] * r, ex[10] * r, ex[11] * r};
        float4 o3 = {ex[12] * r, ex[13] * r, ex[14] * r, ex[15] * r};
        float4* og = (float4*)(out + (row0 + t) * NE);
        og[0] = o0; og[1] = o1; og[2] = o2; og[3] = o3;
    }
}

// ---- Pass B: bit-exact (round-2 order) recompute of flagged rows (verbatim r5) ----
__global__ __launch_bounds__(256)
void fixup_k(const float* __restrict__ x,
             const float* __restrict__ w1,
             const float* __restrict__ b1,
             const float* __restrict__ w2,
             const float* __restrict__ b2,
             float* __restrict__ out,
             const unsigned* __restrict__ cntp,
             const unsigned* __restrict__ ids,
             unsigned cap)
{
    const int lane = threadIdx.x & 63;
    const int gw   = (int)((blockIdx.x * 256 + threadIdx.x) >> 6);
    const int nw   = (int)((gridDim.x * 256) >> 6);
    unsigned n = *cntp; if (n > cap) n = cap;
    const int c = lane & 15;
    const int g = lane >> 4;

    for (unsigned wi = gw; wi < n; wi += nw) {
        unsigned row = ids[wi];
        const float* xr = x + (size_t)row * DIN;
        const int nh0 = 128 * g;
        int cols[8];
#pragma unroll
        for (int j = 0; j < 8; ++j)
            cols[j] = nh0 + c * 4 + (j & 3) + ((j >> 2) << 6);

        float a[8];
#pragma unroll
        for (int j = 0; j < 8; ++j) a[j] = 0.f;
        for (int k4 = 0; k4 < 64; ++k4) {
            float4 xv = *(const float4*)(xr + k4 * 4);
            const float* wp = w1 + (size_t)(k4 * 4) * DHID;
#pragma unroll
            for (int j = 0; j < 8; ++j) {
                a[j] = fmaf(xv.x, wp[cols[j]],            a[j]);
                a[j] = fmaf(xv.y, wp[DHID + cols[j]],     a[j]);
                a[j] = fmaf(xv.z, wp[2 * DHID + cols[j]], a[j]);
                a[j] = fmaf(xv.w, wp[3 * DHID + cols[j]], a[j]);
            }
        }
        float h[8];
#pragma unroll
        for (int j = 0; j < 8; ++j) h[j] = fmaxf(a[j] + b1[cols[j]], 0.f);

        float l[NE];
#pragma unroll 1
        for (int e = 0; e < NE; ++e) {
            float p = 0.f;
#pragma unroll
            for (int j = 0; j < 8; ++j)
                p = fmaf(h[j], w2[cols[j] * NE + e], p);
            p += __shfl_xor(p, 1, 64);
            p += __shfl_xor(p, 2, 64);
            p += __shfl_xor(p, 4, 64);
            p += __shfl_xor(p, 8, 64);
            float t0 = __shfl(p, 0 * 16 + e, 64);
            float t1 = __shfl(p, 1 * 16 + e, 64);
            float t2 = __shfl(p, 2 * 16 + e, 64);
            float t3 = __shfl(p, 3 * 16 + e, 64);
            l[e] = (((t0 + t1) + t2) + t3) + b2[e];
        }

        if (lane == 0) {
            float m1 = -INFINITY; int i1 = 0;
#pragma unroll
            for (int e = 0; e < NE; ++e)
                if (l[e] > m1) { m1 = l[e]; i1 = e; }
            float m2 = -INFINITY; int i2 = -1;
#pragma unroll
            for (int e = 0; e < NE; ++e)
                if (e != i1 && l[e] > m2) { m2 = l[e]; i2 = e; }
            float s[NE];
#pragma unroll
            for (int e = 0; e < NE; ++e)
                s[e] = (e == i1 || e == i2) ? l[e] : 0.f;
            float mx = s[0];
#pragma unroll
            for (int e = 1; e < NE; ++e) mx = fmaxf(mx, s[e]);
            float ex[NE];
            float sum = 0.f;
#pragma unroll
            for (int e = 0; e < NE; ++e) { ex[e] = expf(s[e] - mx); sum += ex[e]; }
            float* og = out + (size_t)row * NE;
#pragma unroll
            for (int e = 0; e < NE; ++e) og[e] = ex[e] / sum;
        }
    }
}

extern "C" void kernel_launch(void* const* d_in, const int* in_sizes, int n_in,
                              void* d_out, int out_size, void* d_ws, size_t ws_size,
                              hipStream_t stream) {
    const float* x  = (const float*)d_in[0];
    const float* w1 = (const float*)d_in[1];
    const float* b1 = (const float*)d_in[2];
    const float* w2 = (const float*)d_in[3];
    const float* b2 = (const float*)d_in[4];
    float* outp = (float*)d_out;

    // ws: [0,512K): w1t (split, LDS-imaged) | [1M): u32 counter | [1M+64): ids
    bf16*     w1t = (bf16*)d_ws;
    unsigned* cnt = (unsigned*)((char*)d_ws + (1u << 20));
    unsigned* ids = (unsigned*)((char*)d_ws + (1u << 20) + 64);
    unsigned  cap = 0;
    if (ws_size > (1u << 20) + 64)
        cap = (unsigned)((ws_size - (1u << 20) - 64) / 4);

    hipMemsetAsync((char*)d_ws + (1u << 20), 0, 4, stream);
    split_w1_k<<<dim3(512), dim3(256), 0, stream>>>(w1, w1t);
    router_mfma_k<<<dim3(NROW / ROWS), dim3(256), 0, stream>>>(
        x, b1, w2, b2, outp, w1t, cnt, ids, cap);
    fixup_k<<<dim3(256), dim3(256), 0, stream>>>(
        x, w1, b1, w2, b2, outp, cnt, ids, cap);
}

// Round 7
// 1369.961 us; speedup vs baseline: 1.0212x; 1.0212x over previous
//
#include <hip/hip_runtime.h>
#include <cmath>

#define NE   16
#define DIN  256
#define DHID 512
#define NROW 524288
#define ROWS 64
#define TAU  4e-4f

typedef __bf16 bf16;
typedef bf16  bf16x8 __attribute__((ext_vector_type(8)));
typedef float f32x4  __attribute__((ext_vector_type(4)));

template<int CTRL>
__device__ __forceinline__ float dpp_xor_add(float v) {
    int s = __builtin_amdgcn_update_dpp(0, __float_as_int(v), CTRL, 0xF, 0xF, true);
    return v + __int_as_float(s);
}
template<int OFF>
__device__ __forceinline__ float swz_xor_add(float v) {
    int s = __builtin_amdgcn_ds_swizzle(__float_as_int(v), OFF);
    return v + __int_as_float(s);
}

// ---- K0: split w1 -> bf16 hi/lo, per-(ch,ksk) slice layout (verbatim round 6) ----
// slice (ch,ksk): 8192 bf16 = [pl 2][g 4][col 128][j 8], slices consecutive.
__global__ __launch_bounds__(256)
void split_w1_k(const float* __restrict__ w1, bf16* __restrict__ w1t) {
    int i = blockIdx.x * 256 + threadIdx.x;   // 131072 elements
    int col = i & 511, k = i >> 9;
    float v = w1[k * DHID + col];
    bf16 h = (bf16)v;
    bf16 l = (bf16)(v - (float)h);
    int ch = col >> 7, cl = col & 127, ksk = k >> 5, g = (k >> 3) & 3, j = k & 7;
    size_t base = (size_t)(ch * 8 + ksk) * 8192;
    w1t[base +        g * 1024 + cl * 8 + j] = h;
    w1t[base + 4096 + g * 1024 + cl * 8 + j] = l;
}

// w fragment loads for slice si into buffer W[4][2]  (8 x 16B per lane, L1/L2-hot)
#define LOADW(W, si)                                                              \
    {                                                                             \
        const bf16* sp = w1t + (size_t)(si) * 8192 + g * 1024 + (64 * wc + c) * 8;\
        _Pragma("unroll")                                                         \
        for (int tj = 0; tj < 4; ++tj) {                                          \
            W[tj][0] = *(const bf16x8*)(sp + tj * 128);                           \
            W[tj][1] = *(const bf16x8*)(sp + tj * 128 + 4096);                    \
        }                                                                         \
    }

// x fragment loads for k-slice kk into buffer X[2][2] from LDS
#define LOADX(X, kk)                                                              \
    {                                                                             \
        _Pragma("unroll")                                                         \
        for (int ti = 0; ti < 2; ++ti) {                                          \
            X[ti][0] = *(const bf16x8*)&xh_s[kk][g][32 * wr + 16 * ti + c][0];    \
            X[ti][1] = *(const bf16x8*)&xl_s[kk][g][32 * wr + 16 * ti + c][0];    \
        }                                                                         \
    }

// bf16x3 MFMA block: hh, hl, lh per (ti,tj)
#define COMPUTE(X, W)                                                             \
    {                                                                             \
        _Pragma("unroll")                                                         \
        for (int tj = 0; tj < 4; ++tj)                                            \
            _Pragma("unroll")                                                     \
            for (int ti = 0; ti < 2; ++ti) {                                      \
                acc[ti][tj] = __builtin_amdgcn_mfma_f32_16x16x32_bf16(X[ti][0], W[tj][0], acc[ti][tj], 0, 0, 0); \
                acc[ti][tj] = __builtin_amdgcn_mfma_f32_16x16x32_bf16(X[ti][0], W[tj][1], acc[ti][tj], 0, 0, 0); \
                acc[ti][tj] = __builtin_amdgcn_mfma_f32_16x16x32_bf16(X[ti][1], W[tj][0], acc[ti][tj], 0, 0, 0); \
            }                                                                     \
    }

// ---- Pass A: barrier-free K-loop MFMA router + gap flagging ----
__global__ __launch_bounds__(256, 2)
void router_mfma_k(const float* __restrict__ x,
                   const float* __restrict__ b1,
                   const float* __restrict__ w2,
                   const float* __restrict__ b2,
                   float* __restrict__ out,
                   const bf16* __restrict__ w1t,
                   unsigned* __restrict__ cnt,
                   unsigned* __restrict__ ids,
                   unsigned cap)
{
    __shared__ __align__(16) bf16 xh_s[8][4][ROWS][8];   // 32 KB  [ksk][g][row][j]
    __shared__ __align__(16) bf16 xl_s[8][4][ROWS][8];   // 32 KB
    __shared__ float l_lds[ROWS][NE + 1];                // 4.25 KB

    const int t    = threadIdx.x;
    const int lane = t & 63;
    const int wv   = t >> 6;
    const int wr   = wv >> 1;          // row-half (rows 32wr..+32)
    const int wc   = wv & 1;           // col-half (cols 64wc..+64)
    const int c    = lane & 15;        // frag lane coord / owned expert
    const int g    = lane >> 4;        // k sub-block / C row sub-group
    const long long row0 = (long long)blockIdx.x * ROWS;

    // ---- stage x (full K=256) split hi/lo, ONCE ----
    {
        const int r = t & 63;
        const int q = t >> 6;                      // k-quarter
        const float* xg = x + (row0 + r) * DIN + q * 64;
#pragma unroll
        for (int m = 0; m < 8; ++m) {
            float4 v0 = ((const float4*)xg)[2 * m];
            float4 v1 = ((const float4*)xg)[2 * m + 1];
            int k   = q * 64 + m * 8;
            int ksk = k >> 5, gg = (k >> 3) & 3;
            float vv[8] = {v0.x, v0.y, v0.z, v0.w, v1.x, v1.y, v1.z, v1.w};
            bf16 hb[8], lb[8];
#pragma unroll
            for (int qq = 0; qq < 8; ++qq) {
                hb[qq] = (bf16)vv[qq];
                lb[qq] = (bf16)(vv[qq] - (float)hb[qq]);
            }
            *(bf16x8*)&xh_s[ksk][gg][r][0] = *(const bf16x8*)hb;
            *(bf16x8*)&xl_s[ksk][gg][r][0] = *(const bf16x8*)lb;
        }
    }
    __syncthreads();   // x_s ready; NO barriers inside the K loop below

    float lg[8];
#pragma unroll
    for (int i = 0; i < 8; ++i) lg[i] = 0.f;

    bf16x8 wA[4][2], wB[4][2], xA[2][2], xB[2][2];
    LOADW(wA, 0);
    LOADX(xA, 0);

    for (int ch = 0; ch < 4; ++ch) {
        f32x4 acc[2][4];
#pragma unroll
        for (int ti = 0; ti < 2; ++ti)
#pragma unroll
            for (int tj = 0; tj < 4; ++tj)
#pragma unroll
                for (int r = 0; r < 4; ++r) acc[ti][tj][r] = 0.f;

        // 8 k-slices, register double-buffered (A computes even, B odd)
#pragma unroll
        for (int kp = 0; kp < 4; ++kp) {
            const int ks0 = 2 * kp;
            int s1 = ch * 8 + ks0 + 1; if (s1 > 31) s1 = 31;
            int s2 = ch * 8 + ks0 + 2; if (s2 > 31) s2 = 31;
            LOADW(wB, s1);
            LOADX(xB, (ks0 + 1) & 7);
            COMPUTE(xA, wA);
            LOADW(wA, s2);
            LOADX(xA, (ks0 + 2) & 7);
            COMPUTE(xB, wB);
        }

        // ---- bias + relu (C row = 32wr+16ti+4g+r, col = 128ch+64wc+16tj+c) ----
#pragma unroll
        for (int tj = 0; tj < 4; ++tj) {
            float bj = b1[128 * ch + 64 * wc + 16 * tj + c];
#pragma unroll
            for (int ti = 0; ti < 2; ++ti)
#pragma unroll
                for (int r = 0; r < 4; ++r)
                    acc[ti][tj][r] = fmaxf(acc[ti][tj][r] + bj, 0.f);
        }

        // ---- fused layer 2 partials (this wave's col-half) ----
#pragma unroll 1
        for (int e = 0; e < NE; ++e) {
            float p[8];
#pragma unroll
            for (int i = 0; i < 8; ++i) p[i] = 0.f;
#pragma unroll
            for (int tj = 0; tj < 4; ++tj) {
                float wvv = w2[(128 * ch + 64 * wc + 16 * tj + c) * NE + e];
#pragma unroll
                for (int ti = 0; ti < 2; ++ti)
#pragma unroll
                    for (int r = 0; r < 4; ++r)
                        p[ti * 4 + r] = fmaf(acc[ti][tj][r], wvv, p[ti * 4 + r]);
            }
#pragma unroll
            for (int i = 0; i < 8; ++i) p[i] = dpp_xor_add<0xB1>(p[i]);
#pragma unroll
            for (int i = 0; i < 8; ++i) p[i] = dpp_xor_add<0x4E>(p[i]);
#pragma unroll
            for (int i = 0; i < 8; ++i) p[i] = swz_xor_add<0x101F>(p[i]);
#pragma unroll
            for (int i = 0; i < 8; ++i) p[i] = swz_xor_add<0x201F>(p[i]);
            if (c == e) {
#pragma unroll
                for (int i = 0; i < 8; ++i) lg[i] += p[i];
            }
        }
    }

    // ---- combine col-halves (fixed order: wc0 writes, wc1 adds) ----
    __syncthreads();
    if (wc == 0) {
        float b2c = b2[c];
#pragma unroll
        for (int ti = 0; ti < 2; ++ti)
#pragma unroll
            for (int r = 0; r < 4; ++r)
                l_lds[32 * wr + 16 * ti + 4 * g + r][c] = lg[ti * 4 + r] + b2c;
    }
    __syncthreads();
    if (wc == 1) {
#pragma unroll
        for (int ti = 0; ti < 2; ++ti)
#pragma unroll
            for (int r = 0; r < 4; ++r)
                l_lds[32 * wr + 16 * ti + 4 * g + r][c] += lg[ti * 4 + r];
    }
    __syncthreads();

    // ---- per-row top-2 + TAU flag + masked softmax ----
    if (t < ROWS) {
        float l[NE];
#pragma unroll
        for (int e = 0; e < NE; ++e) l[e] = l_lds[t][e];

        float m1 = -INFINITY; int i1 = 0;
#pragma unroll
        for (int e = 0; e < NE; ++e)
            if (l[e] > m1) { m1 = l[e]; i1 = e; }
        float m2 = -INFINITY; int i2 = -1;
#pragma unroll
        for (int e = 0; e < NE; ++e)
            if (e != i1 && l[e] > m2) { m2 = l[e]; i2 = e; }
        float m3 = -INFINITY;
#pragma unroll
        for (int e = 0; e < NE; ++e)
            if (e != i1 && e != i2 && l[e] > m3) m3 = l[e];

        if (m2 - m3 < TAU) {
            unsigned idx = atomicAdd(cnt, 1u);
            if (idx < cap) ids[idx] = (unsigned)(row0 + t);
        }

        float s[NE];
#pragma unroll
        for (int e = 0; e < NE; ++e)
            s[e] = (e == i1 || e == i2) ? l[e] : 0.f;
        float mx = s[0];
#pragma unroll
        for (int e = 1; e < NE; ++e) mx = fmaxf(mx, s[e]);
        float ex[NE];
        float sum = 0.f;
#pragma unroll
        for (int e = 0; e < NE; ++e) { ex[e] = expf(s[e] - mx); sum += ex[e]; }
        float r = 1.f / sum;
        float4 o0 = {ex[0] * r, ex[1] * r, ex[2] * r, ex[3] * r};
        float4 o1 = {ex[4] * r, ex[5] * r, ex[6] * r, ex[7] * r};
        float4 o2 = {ex[8] * r, ex[9] * r, ex[10] * r, ex[11] * r};
        float4 o3 = {ex[12] * r, ex[13] * r, ex[14] * r, ex[15] * r};
        float4* og = (float4*)(out + (row0 + t) * NE);
        og[0] = o0; og[1] = o1; og[2] = o2; og[3] = o3;
    }
}

// ---- Pass B: bit-exact (round-2 order) recompute of flagged rows (verbatim) ----
__global__ __launch_bounds__(256)
void fixup_k(const float* __restrict__ x,
             const float* __restrict__ w1,
             const float* __restrict__ b1,
             const float* __restrict__ w2,
             const float* __restrict__ b2,
             float* __restrict__ out,
             const unsigned* __restrict__ cntp,
             const unsigned* __restrict__ ids,
             unsigned cap)
{
    const int lane = threadIdx.x & 63;
    const int gw   = (int)((blockIdx.x * 256 + threadIdx.x) >> 6);
    const int nw   = (int)((gridDim.x * 256) >> 6);
    unsigned n = *cntp; if (n > cap) n = cap;
    const int c = lane & 15;
    const int g = lane >> 4;

    for (unsigned wi = gw; wi < n; wi += nw) {
        unsigned row = ids[wi];
        const float* xr = x + (size_t)row * DIN;
        const int nh0 = 128 * g;
        int cols[8];
#pragma unroll
        for (int j = 0; j < 8; ++j)
            cols[j] = nh0 + c * 4 + (j & 3) + ((j >> 2) << 6);

        float a[8];
#pragma unroll
        for (int j = 0; j < 8; ++j) a[j] = 0.f;
        for (int k4 = 0; k4 < 64; ++k4) {
            float4 xv = *(const float4*)(xr + k4 * 4);
            const float* wp = w1 + (size_t)(k4 * 4) * DHID;
#pragma unroll
            for (int j = 0; j < 8; ++j) {
                a[j] = fmaf(xv.x, wp[cols[j]],            a[j]);
                a[j] = fmaf(xv.y, wp[DHID + cols[j]],     a[j]);
                a[j] = fmaf(xv.z, wp[2 * DHID + cols[j]], a[j]);
                a[j] = fmaf(xv.w, wp[3 * DHID + cols[j]], a[j]);
            }
        }
        float h[8];
#pragma unroll
        for (int j = 0; j < 8; ++j) h[j] = fmaxf(a[j] + b1[cols[j]], 0.f);

        float l[NE];
#pragma unroll 1
        for (int e = 0; e < NE; ++e) {
            float p = 0.f;
#pragma unroll
            for (int j = 0; j < 8; ++j)
                p = fmaf(h[j], w2[cols[j] * NE + e], p);
            p += __shfl_xor(p, 1, 64);
            p += __shfl_xor(p, 2, 64);
            p += __shfl_xor(p, 4, 64);
            p += __shfl_xor(p, 8, 64);
            float t0 = __shfl(p, 0 * 16 + e, 64);
            float t1 = __shfl(p, 1 * 16 + e, 64);
            float t2 = __shfl(p, 2 * 16 + e, 64);
            float t3 = __shfl(p, 3 * 16 + e, 64);
            l[e] = (((t0 + t1) + t2) + t3) + b2[e];
        }

        if (lane == 0) {
            float m1 = -INFINITY; int i1 = 0;
#pragma unroll
            for (int e = 0; e < NE; ++e)
                if (l[e] > m1) { m1 = l[e]; i1 = e; }
            float m2 = -INFINITY; int i2 = -1;
#pragma unroll
            for (int e = 0; e < NE; ++e)
                if (e != i1 && l[e] > m2) { m2 = l[e]; i2 = e; }
            float s[NE];
#pragma unroll
            for (int e = 0; e < NE; ++e)
                s[e] = (e == i1 || e == i2) ? l[e] : 0.f;
            float mx = s[0];
#pragma unroll
            for (int e = 1; e < NE; ++e) mx = fmaxf(mx, s[e]);
            float ex[NE];
            float sum = 0.f;
#pragma unroll
            for (int e = 0; e < NE; ++e) { ex[e] = expf(s[e] - mx); sum += ex[e]; }
            float* og = out + (size_t)row * NE;
#pragma unroll
            for (int e = 0; e < NE; ++e) og[e] = ex[e] / sum;
        }
    }
}

extern "C" void kernel_launch(void* const* d_in, const int* in_sizes, int n_in,
                              void* d_out, int out_size, void* d_ws, size_t ws_size,
                              hipStream_t stream) {
    const float* x  = (const float*)d_in[0];
    const float* w1 = (const float*)d_in[1];
    const float* b1 = (const float*)d_in[2];
    const float* w2 = (const float*)d_in[3];
    const float* b2 = (const float*)d_in[4];
    float* outp = (float*)d_out;

    // ws: [0,512K): w1t (split, slice-imaged) | [1M): u32 counter | [1M+64): ids
    bf16*     w1t = (bf16*)d_ws;
    unsigned* cnt = (unsigned*)((char*)d_ws + (1u << 20));
    unsigned* ids = (unsigned*)((char*)d_ws + (1u << 20) + 64);
    unsigned  cap = 0;
    if (ws_size > (1u << 20) + 64)
        cap = (unsigned)((ws_size - (1u << 20) - 64) / 4);

    hipMemsetAsync((char*)d_ws + (1u << 20), 0, 4, stream);
    split_w1_k<<<dim3(512), dim3(256), 0, stream>>>(w1, w1t);
    router_mfma_k<<<dim3(NROW / ROWS), dim3(256), 0, stream>>>(
        x, b1, w2, b2, outp, w1t, cnt, ids, cap);
    fixup_k<<<dim3(256), dim3(256), 0, stream>>>(
        x, w1, b1, w2, b2, outp, cnt, ids, cap);
}

// Round 9
// 1359.610 us; speedup vs baseline: 1.0289x; 1.0076x over previous
//
#include <hip/hip_runtime.h>
#include <cmath>

#define NE   16
#define DIN  256
#define DHID 512
#define NROW 524288
#define ROWS 64
#define TAU  4e-4f

typedef __bf16 bf16;
typedef bf16  bf16x8 __attribute__((ext_vector_type(8)));
typedef float f32x4  __attribute__((ext_vector_type(4)));

template<int CTRL>
__device__ __forceinline__ float dpp_xor_add(float v) {
    int s = __builtin_amdgcn_update_dpp(0, __float_as_int(v), CTRL, 0xF, 0xF, true);
    return v + __int_as_float(s);
}
template<int OFF>
__device__ __forceinline__ float swz_xor_add(float v) {
    int s = __builtin_amdgcn_ds_swizzle(__float_as_int(v), OFF);
    return v + __int_as_float(s);
}

// ---- K0: split w1 -> bf16 hi/lo, per-(ch,ksk) slice layout (verbatim r6/r7) ----
// slice (ch,ksk): 8192 bf16 = [pl 2][g 4][col 128][j 8], slices consecutive.
__global__ __launch_bounds__(256)
void split_w1_k(const float* __restrict__ w1, bf16* __restrict__ w1t) {
    int i = blockIdx.x * 256 + threadIdx.x;   // 131072 elements
    int col = i & 511, k = i >> 9;
    float v = w1[k * DHID + col];
    bf16 h = (bf16)v;
    bf16 l = (bf16)(v - (float)h);
    int ch = col >> 7, cl = col & 127, ksk = k >> 5, g = (k >> 3) & 3, j = k & 7;
    size_t base = (size_t)(ch * 8 + ksk) * 8192;
    w1t[base +        g * 1024 + cl * 8 + j] = h;
    w1t[base + 4096 + g * 1024 + cl * 8 + j] = l;
}

// w fragment loads for slice si into buffer W[4][2]  (8 x 16B per lane, L2-hot)  [verbatim r7]
#define LOADW(W, si)                                                              \
    {                                                                             \
        const bf16* sp = w1t + (size_t)(si) * 8192 + g * 1024 + (64 * wc + c) * 8;\
        _Pragma("unroll")                                                         \
        for (int tj = 0; tj < 4; ++tj) {                                          \
            W[tj][0] = *(const bf16x8*)(sp + tj * 128);                           \
            W[tj][1] = *(const bf16x8*)(sp + tj * 128 + 4096);                    \
        }                                                                         \
    }

// x fragment loads for k-slice kk into buffer X[2][2] from LDS  [verbatim r7]
#define LOADX(X, kk)                                                              \
    {                                                                             \
        _Pragma("unroll")                                                         \
        for (int ti = 0; ti < 2; ++ti) {                                          \
            X[ti][0] = *(const bf16x8*)&xh_s[kk][g][32 * wr + 16 * ti + c][0];    \
            X[ti][1] = *(const bf16x8*)&xl_s[kk][g][32 * wr + 16 * ti + c][0];    \
        }                                                                         \
    }

// bf16x3 MFMA block: hh, hl, lh per (ti,tj)  [verbatim r7]
#define COMPUTE(X, W)                                                             \
    {                                                                             \
        _Pragma("unroll")                                                         \
        for (int tj = 0; tj < 4; ++tj)                                            \
            _Pragma("unroll")                                                     \
            for (int ti = 0; ti < 2; ++ti) {                                      \
                acc[ti][tj] = __builtin_amdgcn_mfma_f32_16x16x32_bf16(X[ti][0], W[tj][0], acc[ti][tj], 0, 0, 0); \
                acc[ti][tj] = __builtin_amdgcn_mfma_f32_16x16x32_bf16(X[ti][0], W[tj][1], acc[ti][tj], 0, 0, 0); \
                acc[ti][tj] = __builtin_amdgcn_mfma_f32_16x16x32_bf16(X[ti][1], W[tj][0], acc[ti][tj], 0, 0, 0); \
            }                                                                     \
    }

// ---- Pass A: r7 structure, W triple-buffered (s+2 prefetch), X double-buffered ----
__global__ __launch_bounds__(256, 2)
void router_mfma_k(const float* __restrict__ x,
                   const float* __restrict__ b1,
                   const float* __restrict__ w2,
                   const float* __restrict__ b2,
                   float* __restrict__ out,
                   const bf16* __restrict__ w1t,
                   unsigned* __restrict__ cnt,
                   unsigned* __restrict__ ids,
                   unsigned cap)
{
    __shared__ __align__(16) bf16 xh_s[8][4][ROWS][8];   // 32 KB  [ksk][g][row][j]
    __shared__ __align__(16) bf16 xl_s[8][4][ROWS][8];   // 32 KB
    __shared__ float l_lds[ROWS][NE + 1];                // 4.25 KB

    const int t    = threadIdx.x;
    const int lane = t & 63;
    const int wv   = t >> 6;
    const int wr   = wv >> 1;          // row-half (rows 32wr..+32)
    const int wc   = wv & 1;           // col-half (cols 64wc..+64)
    const int c    = lane & 15;        // frag lane coord / owned expert
    const int g    = lane >> 4;        // k sub-block / C row sub-group
    const long long row0 = (long long)blockIdx.x * ROWS;

    // W preloads issued BEFORE x staging: L2 latency hides under the staging work
    bf16x8 Wb[3][4][2], Xb[2][2][2];
    LOADW(Wb[0], 0);
    LOADW(Wb[1], 1);

    // ---- stage x (full K=256) split hi/lo, ONCE (verbatim r7) ----
    {
        const int r = t & 63;
        const int q = t >> 6;                      // k-quarter
        const float* xg = x + (row0 + r) * DIN + q * 64;
#pragma unroll
        for (int m = 0; m < 8; ++m) {
            float4 v0 = ((const float4*)xg)[2 * m];
            float4 v1 = ((const float4*)xg)[2 * m + 1];
            int k   = q * 64 + m * 8;
            int ksk = k >> 5, gg = (k >> 3) & 3;
            float vv[8] = {v0.x, v0.y, v0.z, v0.w, v1.x, v1.y, v1.z, v1.w};
            bf16 hb[8], lb[8];
#pragma unroll
            for (int qq = 0; qq < 8; ++qq) {
                hb[qq] = (bf16)vv[qq];
                lb[qq] = (bf16)(vv[qq] - (float)hb[qq]);
            }
            *(bf16x8*)&xh_s[ksk][gg][r][0] = *(const bf16x8*)hb;
            *(bf16x8*)&xl_s[ksk][gg][r][0] = *(const bf16x8*)lb;
        }
    }
    __syncthreads();   // x_s ready; no barriers in the K loop

    LOADX(Xb[0], 0);

    float lg[8];
#pragma unroll
    for (int i = 0; i < 8; ++i) lg[i] = 0.f;

    f32x4 acc[2][4];

#pragma unroll
    for (int ch = 0; ch < 4; ++ch) {
#pragma unroll
        for (int ti = 0; ti < 2; ++ti)
#pragma unroll
            for (int tj = 0; tj < 4; ++tj)
#pragma unroll
                for (int r = 0; r < 4; ++r) acc[ti][tj][r] = 0.f;

#pragma unroll
        for (int ks = 0; ks < 8; ++ks) {
            const int s  = ch * 8 + ks;                    // compile-time constant
            const int sp2 = (s + 2 > 31) ? 31 : (s + 2);   // W prefetch slice (clamped)
            LOADW(Wb[(s + 2) % 3], sp2);                   // ~230 cyc of MFMA ahead of use
            LOADX(Xb[(s + 1) & 1], (s + 1) & 7);           // ~115 cyc ahead of use
            COMPUTE(Xb[s & 1], Wb[s % 3]);                 // slice s: x slice (s&7) x w slice s
        }

        // ---- bias + relu (verbatim r7) ----
#pragma unroll
        for (int tj = 0; tj < 4; ++tj) {
            float bj = b1[128 * ch + 64 * wc + 16 * tj + c];
#pragma unroll
            for (int ti = 0; ti < 2; ++ti)
#pragma unroll
                for (int r = 0; r < 4; ++r)
                    acc[ti][tj][r] = fmaxf(acc[ti][tj][r] + bj, 0.f);
        }

        // ---- fused layer 2 partials (verbatim r7) ----
#pragma unroll 1
        for (int e = 0; e < NE; ++e) {
            float p[8];
#pragma unroll
            for (int i = 0; i < 8; ++i) p[i] = 0.f;
#pragma unroll
            for (int tj = 0; tj < 4; ++tj) {
                float wvv = w2[(128 * ch + 64 * wc + 16 * tj + c) * NE + e];
#pragma unroll
                for (int ti = 0; ti < 2; ++ti)
#pragma unroll
                    for (int r = 0; r < 4; ++r)
                        p[ti * 4 + r] = fmaf(acc[ti][tj][r], wvv, p[ti * 4 + r]);
            }
#pragma unroll
            for (int i = 0; i < 8; ++i) p[i] = dpp_xor_add<0xB1>(p[i]);
#pragma unroll
            for (int i = 0; i < 8; ++i) p[i] = dpp_xor_add<0x4E>(p[i]);
#pragma unroll
            for (int i = 0; i < 8; ++i) p[i] = swz_xor_add<0x101F>(p[i]);
#pragma unroll
            for (int i = 0; i < 8; ++i) p[i] = swz_xor_add<0x201F>(p[i]);
            if (c == e) {
#pragma unroll
                for (int i = 0; i < 8; ++i) lg[i] += p[i];
            }
        }
    }

    // ---- combine col-halves (verbatim r7: wc0 writes, wc1 adds) ----
    __syncthreads();
    if (wc == 0) {
        float b2c = b2[c];
#pragma unroll
        for (int ti = 0; ti < 2; ++ti)
#pragma unroll
            for (int r = 0; r < 4; ++r)
                l_lds[32 * wr + 16 * ti + 4 * g + r][c] = lg[ti * 4 + r] + b2c;
    }
    __syncthreads();
    if (wc == 1) {
#pragma unroll
        for (int ti = 0; ti < 2; ++ti)
#pragma unroll
            for (int r = 0; r < 4; ++r)
                l_lds[32 * wr + 16 * ti + 4 * g + r][c] += lg[ti * 4 + r];
    }
    __syncthreads();

    // ---- per-row top-2 + TAU flag + masked softmax (verbatim r7) ----
    if (t < ROWS) {
        float l[NE];
#pragma unroll
        for (int e = 0; e < NE; ++e) l[e] = l_lds[t][e];

        float m1 = -INFINITY; int i1 = 0;
#pragma unroll
        for (int e = 0; e < NE; ++e)
            if (l[e] > m1) { m1 = l[e]; i1 = e; }
        float m2 = -INFINITY; int i2 = -1;
#pragma unroll
        for (int e = 0; e < NE; ++e)
            if (e != i1 && l[e] > m2) { m2 = l[e]; i2 = e; }
        float m3 = -INFINITY;
#pragma unroll
        for (int e = 0; e < NE; ++e)
            if (e != i1 && e != i2 && l[e] > m3) m3 = l[e];

        if (m2 - m3 < TAU) {
            unsigned idx = atomicAdd(cnt, 1u);
            if (idx < cap) ids[idx] = (unsigned)(row0 + t);
        }

        float s[NE];
#pragma unroll
        for (int e = 0; e < NE; ++e)
            s[e] = (e == i1 || e == i2) ? l[e] : 0.f;
        float mx = s[0];
#pragma unroll
        for (int e = 1; e < NE; ++e) mx = fmaxf(mx, s[e]);
        float ex[NE];
        float sum = 0.f;
#pragma unroll
        for (int e = 0; e < NE; ++e) { ex[e] = expf(s[e] - mx); sum += ex[e]; }
        float r = 1.f / sum;
        float4 o0 = {ex[0] * r, ex[1] * r, ex[2] * r, ex[3] * r};
        float4 o1 = {ex[4] * r, ex[5] * r, ex[6] * r, ex[7] * r};
        float4 o2 = {ex[8] * r, ex[9] * r, ex[10] * r, ex[11] * r};
        float4 o3 = {ex[12] * r, ex[13] * r, ex[14] * r, ex[15] * r};
        float4* og = (float4*)(out + (row0 + t) * NE);
        og[0] = o0; og[1] = o1; og[2] = o2; og[3] = o3;
    }
}

// ---- Pass B: bit-exact (round-2 order) recompute of flagged rows (FROZEN) ----
__global__ __launch_bounds__(256)
void fixup_k(const float* __restrict__ x,
             const float* __restrict__ w1,
             const float* __restrict__ b1,
             const float* __restrict__ w2,
             const float* __restrict__ b2,
             float* __restrict__ out,
             const unsigned* __restrict__ cntp,
             const unsigned* __restrict__ ids,
             unsigned cap)
{
    const int lane = threadIdx.x & 63;
    const int gw   = (int)((blockIdx.x * 256 + threadIdx.x) >> 6);
    const int nw   = (int)((gridDim.x * 256) >> 6);
    unsigned n = *cntp; if (n > cap) n = cap;
    const int c = lane & 15;
    const int g = lane >> 4;

    for (unsigned wi = gw; wi < n; wi += nw) {
        unsigned row = ids[wi];
        const float* xr = x + (size_t)row * DIN;
        const int nh0 = 128 * g;
        int cols[8];
#pragma unroll
        for (int j = 0; j < 8; ++j)
            cols[j] = nh0 + c * 4 + (j & 3) + ((j >> 2) << 6);

        float a[8];
#pragma unroll
        for (int j = 0; j < 8; ++j) a[j] = 0.f;
        for (int k4 = 0; k4 < 64; ++k4) {
            float4 xv = *(const float4*)(xr + k4 * 4);
            const float* wp = w1 + (size_t)(k4 * 4) * DHID;
#pragma unroll
            for (int j = 0; j < 8; ++j) {
                a[j] = fmaf(xv.x, wp[cols[j]],            a[j]);
                a[j] = fmaf(xv.y, wp[DHID + cols[j]],     a[j]);
                a[j] = fmaf(xv.z, wp[2 * DHID + cols[j]], a[j]);
                a[j] = fmaf(xv.w, wp[3 * DHID + cols[j]], a[j]);
            }
        }
        float h[8];
#pragma unroll
        for (int j = 0; j < 8; ++j) h[j] = fmaxf(a[j] + b1[cols[j]], 0.f);

        float l[NE];
#pragma unroll 1
        for (int e = 0; e < NE; ++e) {
            float p = 0.f;
#pragma unroll
            for (int j = 0; j < 8; ++j)
                p = fmaf(h[j], w2[cols[j] * NE + e], p);
            p += __shfl_xor(p, 1, 64);
            p += __shfl_xor(p, 2, 64);
            p += __shfl_xor(p, 4, 64);
            p += __shfl_xor(p, 8, 64);
            float t0 = __shfl(p, 0 * 16 + e, 64);
            float t1 = __shfl(p, 1 * 16 + e, 64);
            float t2 = __shfl(p, 2 * 16 + e, 64);
            float t3 = __shfl(p, 3 * 16 + e, 64);
            l[e] = (((t0 + t1) + t2) + t3) + b2[e];
        }

        if (lane == 0) {
            float m1 = -INFINITY; int i1 = 0;
#pragma unroll
            for (int e = 0; e < NE; ++e)
                if (l[e] > m1) { m1 = l[e]; i1 = e; }
            float m2 = -INFINITY; int i2 = -1;
#pragma unroll
            for (int e = 0; e < NE; ++e)
                if (e != i1 && l[e] > m2) { m2 = l[e]; i2 = e; }
            float s[NE];
#pragma unroll
            for (int e = 0; e < NE; ++e)
                s[e] = (e == i1 || e == i2) ? l[e] : 0.f;
            float mx = s[0];
#pragma unroll
            for (int e = 1; e < NE; ++e) mx = fmaxf(mx, s[e]);
            float ex[NE];
            float sum = 0.f;
#pragma unroll
            for (int e = 0; e < NE; ++e) { ex[e] = expf(s[e] - mx); sum += ex[e]; }
            float* og = out + (size_t)row * NE;
#pragma unroll
            for (int e = 0; e < NE; ++e) og[e] = ex[e] / sum;
        }
    }
}

extern "C" void kernel_launch(void* const* d_in, const int* in_sizes, int n_in,
                              void* d_out, int out_size, void* d_ws, size_t ws_size,
                              hipStream_t stream) {
    const float* x  = (const float*)d_in[0];
    const float* w1 = (const float*)d_in[1];
    const float* b1 = (const float*)d_in[2];
    const float* w2 = (const float*)d_in[3];
    const float* b2 = (const float*)d_in[4];
    float* outp = (float*)d_out;

    // ws: [0,512K): w1t (split, slice-imaged) | [1M): u32 counter | [1M+64): ids
    bf16*     w1t = (bf16*)d_ws;
    unsigned* cnt = (unsigned*)((char*)d_ws + (1u << 20));
    unsigned* ids = (unsigned*)((char*)d_ws + (1u << 20) + 64);
    unsigned  cap = 0;
    if (ws_size > (1u << 20) + 64)
        cap = (unsigned)((ws_size - (1u << 20) - 64) / 4);

    hipMemsetAsync((char*)d_ws + (1u << 20), 0, 4, stream);
    split_w1_k<<<dim3(512), dim3(256), 0, stream>>>(w1, w1t);
    router_mfma_k<<<dim3(NROW / ROWS), dim3(256), 0, stream>>>(
        x, b1, w2, b2, outp, w1t, cnt, ids, cap);
    fixup_k<<<dim3(256), dim3(256), 0, stream>>>(
        x, w1, b1, w2, b2, outp, cnt, ids, cap);
}